// Round 1
// baseline (2936.617 us; speedup 1.0000x reference)
//
#include <hip/hip_runtime.h>
#include <math.h>

#define C_CLS 40
#define RPB 6   // rows per 256-thread block (6*40=240 active threads)

// ---- runtime mask element-size handling ------------------------------------
static __device__ __forceinline__ bool load_mask(const void* p, int esz, int i) {
  if (esz == 1) return ((const unsigned char*)p)[i] != 0;
  return ((const unsigned int*)p)[i] != 0u;  // works for int32 0/1 and f32 0.0/1.0
}

__global__ void detect_kernel(const unsigned int* m, int* flag) {
  __shared__ int bad;
  if (threadIdx.x == 0) bad = 0;
  __syncthreads();
  unsigned int v = m[threadIdx.x];
  if (!(v == 0u || v == 1u || v == 0x3F800000u)) bad = 1;  // benign race
  __syncthreads();
  if (threadIdx.x == 0) flag[0] = bad ? 1 : 4;  // element size in bytes
}

// ---- CSR build -------------------------------------------------------------
__global__ void hist_kernel(const int* __restrict__ row, const float* __restrict__ w,
                            float* __restrict__ deg, int* __restrict__ cnt, int E) {
  int e = blockIdx.x * blockDim.x + threadIdx.x;
  if (e < E) {
    int r = row[e];
    atomicAdd(&deg[r], w[e]);
    atomicAdd(&cnt[r], 1);
  }
}

__global__ void rsqrt_kernel(float* deg, int n) {
  int i = blockIdx.x * blockDim.x + threadIdx.x;
  if (i < n) {
    float d = deg[i];
    deg[i] = (d > 0.f) ? rsqrtf(d) : 0.f;  // deg becomes dis
  }
}

__global__ void scan1_kernel(const int* __restrict__ cnt, int* __restrict__ rp,
                             int* __restrict__ part, int n) {
  __shared__ int sh[256];
  int gid = blockIdx.x * 256 + threadIdx.x;
  int v = (gid < n) ? cnt[gid] : 0;
  sh[threadIdx.x] = v;
  __syncthreads();
  for (int o = 1; o < 256; o <<= 1) {
    int t = (threadIdx.x >= o) ? sh[threadIdx.x - o] : 0;
    __syncthreads();
    sh[threadIdx.x] += t;
    __syncthreads();
  }
  if (gid < n) rp[gid] = sh[threadIdx.x] - v;  // exclusive within block
  if (threadIdx.x == 255) part[blockIdx.x] = sh[255];
}

__global__ void scan2_kernel(int* part, int B) {
  __shared__ int sh[1024];
  int t = threadIdx.x;
  int v = (t < B) ? part[t] : 0;
  sh[t] = v;
  __syncthreads();
  for (int o = 1; o < 1024; o <<= 1) {
    int u = (t >= o) ? sh[t - o] : 0;
    __syncthreads();
    sh[t] += u;
    __syncthreads();
  }
  if (t < B) part[t] = sh[t] - v;  // exclusive block offsets
}

__global__ void scan3_kernel(int* __restrict__ rp, int* __restrict__ cur,
                             const int* __restrict__ part, int n, int E) {
  int gid = blockIdx.x * 256 + threadIdx.x;
  if (gid < n) {
    int v = rp[gid] + part[blockIdx.x];
    rp[gid] = v;
    cur[gid] = v;
  }
  if (gid == 0) rp[n] = E;
}

__global__ void scatter_kernel(const int* __restrict__ row, const int* __restrict__ col,
                               const float* __restrict__ w, const float* __restrict__ dis,
                               int* __restrict__ cursor, int* __restrict__ col_s,
                               float* __restrict__ norm_s, int E) {
  int e = blockIdx.x * blockDim.x + threadIdx.x;
  if (e < E) {
    int r = row[e], c = col[e];
    int pos = atomicAdd(&cursor[r], 1);
    col_s[pos] = c;
    norm_s[pos] = dis[r] * w[e] * dis[c];
  }
}

// ---- error init + sigma numerator ------------------------------------------
__global__ void init_error_kernel(float* __restrict__ x, const float* __restrict__ ysoft,
                                  const int* __restrict__ ytrue, const void* maskp,
                                  const int* __restrict__ flag, float* sig, int n) {
  int idx = blockIdx.x * blockDim.x + threadIdx.x;
  float e = 0.f;
  if (idx < n * C_CLS) {
    int i = idx / C_CLS;
    int c = idx - i * C_CLS;
    if (load_mask(maskp, flag[0], i)) {
      e = ((ytrue[i] == c) ? 1.f : 0.f) - ysoft[idx];
    }
    x[idx] = e;
  }
  // block reduction of |e| -> one atomic per block (keeps f32 sum accurate)
  float a = fabsf(e);
  for (int o = 32; o > 0; o >>= 1) a += __shfl_down(a, o);
  __shared__ float sw[4];
  int lane = threadIdx.x & 63, wv = threadIdx.x >> 6;
  if (lane == 0) sw[wv] = a;
  __syncthreads();
  if (threadIdx.x == 0) atomicAdd(sig, sw[0] + sw[1] + sw[2] + sw[3]);
}

__global__ void count_mask_kernel(const void* maskp, const int* __restrict__ flag,
                                  int* numel, int n) {
  int i = blockIdx.x * blockDim.x + threadIdx.x;
  int v = 0;
  if (i < n && load_mask(maskp, flag[0], i)) v = 1;
  for (int o = 32; o > 0; o >>= 1) v += __shfl_down(v, o);
  __shared__ int sw[4];
  int lane = threadIdx.x & 63, wv = threadIdx.x >> 6;
  if (lane == 0) sw[wv] = v;
  __syncthreads();
  if (threadIdx.x == 0) atomicAdd(numel, sw[0] + sw[1] + sw[2] + sw[3]);
}

// ---- propagation step: POST 0 = clip[-1,1], 1 = row softmax ----------------
template <int POST>
__global__ void __launch_bounds__(256) prop_step(const float* __restrict__ xin,
                                                 float* __restrict__ xout,
                                                 const int* __restrict__ rp,
                                                 const int* __restrict__ cs,
                                                 const float* __restrict__ ns,
                                                 float alpha, int n) {
  int t = threadIdx.x;
  int lr = t / C_CLS;
  int c = t - lr * C_CLS;
  int i = blockIdx.x * RPB + lr;
  bool active = (lr < RPB) && (i < n);
  float v = 0.f;
  if (active) {
    int e0 = rp[i], e1 = rp[i + 1];
    float self = xin[i * C_CLS + c];
    float acc = 0.f;
    for (int e = e0; e < e1; ++e) {
      acc = fmaf(ns[e], xin[cs[e] * C_CLS + c], acc);
    }
    v = alpha * acc + (1.f - alpha) * self;
  }
  if (POST == 0) {
    if (active) xout[i * C_CLS + c] = fminf(1.f, fmaxf(-1.f, v));
  } else {
    __shared__ float sh[RPB][C_CLS];
    __shared__ float shm[RPB], shs[RPB];
    if (active) sh[lr][c] = v;
    __syncthreads();
    if (active && c == 0) {
      float m = sh[lr][0];
#pragma unroll
      for (int k = 1; k < C_CLS; ++k) m = fmaxf(m, sh[lr][k]);
      float s = 0.f;
#pragma unroll
      for (int k = 0; k < C_CLS; ++k) s += __expf(sh[lr][k] - m);
      shm[lr] = m;
      shs[lr] = s;
    }
    __syncthreads();
    if (active) xout[i * C_CLS + c] = __expf(v - shm[lr]) / shs[lr];
  }
}

// ---- scale + y_s -----------------------------------------------------------
__global__ void __launch_bounds__(256) scale_kernel(const float* __restrict__ sm,
                                                    float* __restrict__ out,
                                                    const float* __restrict__ ysoft,
                                                    const int* __restrict__ ytrue,
                                                    const void* maskp,
                                                    const int* __restrict__ flag,
                                                    const float* __restrict__ sig,
                                                    const int* __restrict__ numel, int n) {
  int t = threadIdx.x;
  int lr = t / C_CLS, c = t - lr * C_CLS;
  int i = blockIdx.x * RPB + lr;
  bool active = (lr < RPB) && (i < n);
  __shared__ float sh[RPB][C_CLS];
  __shared__ float shd[RPB];
  float v = 0.f;
  if (active) {
    v = sm[i * C_CLS + c];
    sh[lr][c] = fabsf(v);
  }
  __syncthreads();
  if (active && c == 0) {
    float d = 0.f;
#pragma unroll
    for (int k = 0; k < C_CLS; ++k) d += sh[lr][k];
    shd[lr] = d;
  }
  __syncthreads();
  if (active) {
    float denom = shd[lr];
    float sigma = sig[0] / (float)numel[0];
    float raw = sigma / ((denom > 0.f) ? denom : 1.f);
    float scale = (denom <= 0.f || raw > 1000.f) ? 1.f : raw;
    float yc = ysoft[i * C_CLS + c] + scale * v;
    float oh = (ytrue[i] == c) ? 1.f : 0.f;
    out[i * C_CLS + c] = load_mask(maskp, flag[0], i) ? oh : yc;
  }
}

// ---- launch ---------------------------------------------------------------
extern "C" void kernel_launch(void* const* d_in, const int* in_sizes, int n_in,
                              void* d_out, int out_size, void* d_ws, size_t ws_size,
                              hipStream_t stream) {
  const int* y_true = (const int*)d_in[0];
  const float* y_soft = (const float*)d_in[1];
  const void* maskp = d_in[2];
  const int* ei = (const int*)d_in[3];
  const float* ew = (const float*)d_in[4];
  const int n = in_sizes[0];
  const int E = in_sizes[4];
  const int* row = ei;
  const int* col = ei + E;

  char* ws = (char*)d_ws;
  size_t o = 0;
  auto alloc = [&](size_t bytes) -> void* {
    void* p = ws + o;
    o += (bytes + 255) & ~(size_t)255;
    return p;
  };
  float* xA = (float*)alloc((size_t)n * C_CLS * 4);
  int* col_s = (int*)alloc((size_t)E * 4);
  float* norm_s = (float*)alloc((size_t)E * 4);
  float* deg = (float*)alloc((size_t)n * 4);   // becomes dis after rsqrt_kernel
  int* cnt = (int*)alloc((size_t)n * 4);
  float* sig = (float*)alloc(4);
  int* numel = (int*)alloc(4);
  int* flag = (int*)alloc(4);
  int* rp = (int*)alloc((size_t)(n + 1) * 4);
  int* cur = (int*)alloc((size_t)n * 4);
  int* part = (int*)alloc(4096);
  float* xB = (float*)d_out;  // d_out doubles as ping-pong buffer

  hipMemsetAsync(deg, 0, (size_t)n * 4, stream);
  hipMemsetAsync(cnt, 0, (size_t)n * 4, stream);
  hipMemsetAsync(sig, 0, 4, stream);
  hipMemsetAsync(numel, 0, 4, stream);

  const int be = (E + 255) / 256;
  const int bn = (n + 255) / 256;
  const int bp = (n + RPB - 1) / RPB;

  detect_kernel<<<1, 256, 0, stream>>>((const unsigned int*)maskp, flag);
  hist_kernel<<<be, 256, 0, stream>>>(row, ew, deg, cnt, E);
  rsqrt_kernel<<<bn, 256, 0, stream>>>(deg, n);
  scan1_kernel<<<bn, 256, 0, stream>>>(cnt, rp, part, n);
  scan2_kernel<<<1, 1024, 0, stream>>>(part, bn);
  scan3_kernel<<<bn, 256, 0, stream>>>(rp, cur, part, n, E);
  scatter_kernel<<<be, 256, 0, stream>>>(row, col, ew, deg, cur, col_s, norm_s, E);
  init_error_kernel<<<(n * C_CLS + 255) / 256, 256, 0, stream>>>(xA, y_soft, y_true,
                                                                 maskp, flag, sig, n);
  count_mask_kernel<<<bn, 256, 0, stream>>>(maskp, flag, numel, n);

  // Phase 1: correct (alpha=0.9, clip). Start a=xA -> after 10 steps result in xA.
  float* a = xA;
  float* b = xB;
  for (int k = 0; k < 10; ++k) {
    prop_step<0><<<bp, 256, 0, stream>>>(a, b, rp, col_s, norm_s, 0.9f, n);
    float* t = a; a = b; b = t;
  }
  // a == xA (smoothed error). Scale + y_s written into d_out.
  scale_kernel<<<bp, 256, 0, stream>>>(a, b, y_soft, y_true, maskp, flag, sig, numel, n);
  { float* t = a; a = b; b = t; }  // a = d_out (y_s), b = xA

  // Phase 2: smooth (alpha=0.8, softmax). 10 steps starting at d_out -> ends in d_out.
  for (int k = 0; k < 10; ++k) {
    prop_step<1><<<bp, 256, 0, stream>>>(a, b, rp, col_s, norm_s, 0.8f, n);
    float* t = a; a = b; b = t;
  }
}

// Round 2
// 1408.023 us; speedup vs baseline: 2.0856x; 2.0856x over previous
//
#include <hip/hip_runtime.h>
#include <math.h>

#define C_CLS 40
#define RPB 6   // rows per 256-thread block in scale_kernel

struct __align__(8) Edge { int c; float w; };

// ---- runtime mask element-size handling ------------------------------------
static __device__ __forceinline__ bool load_mask(const void* p, int esz, int i) {
  if (esz == 1) return ((const unsigned char*)p)[i] != 0;
  return ((const unsigned int*)p)[i] != 0u;  // works for int32 0/1 and f32 0.0/1.0
}

__global__ void detect_kernel(const unsigned int* m, int* flag) {
  __shared__ int bad;
  if (threadIdx.x == 0) bad = 0;
  __syncthreads();
  unsigned int v = m[threadIdx.x];
  if (!(v == 0u || v == 1u || v == 0x3F800000u)) bad = 1;  // benign race
  __syncthreads();
  if (threadIdx.x == 0) flag[0] = bad ? 1 : 4;  // element size in bytes
}

// ---- CSR build -------------------------------------------------------------
__global__ void hist_kernel(const int* __restrict__ row, const float* __restrict__ w,
                            float* __restrict__ deg, int* __restrict__ cnt, int E) {
  int e = blockIdx.x * blockDim.x + threadIdx.x;
  if (e < E) {
    int r = row[e];
    atomicAdd(&deg[r], w[e]);
    atomicAdd(&cnt[r], 1);
  }
}

__global__ void rsqrt_kernel(float* deg, int n) {
  int i = blockIdx.x * blockDim.x + threadIdx.x;
  if (i < n) {
    float d = deg[i];
    deg[i] = (d > 0.f) ? rsqrtf(d) : 0.f;  // deg becomes dis
  }
}

__global__ void scan1_kernel(const int* __restrict__ cnt, int* __restrict__ rp,
                             int* __restrict__ part, int n) {
  __shared__ int sh[256];
  int gid = blockIdx.x * 256 + threadIdx.x;
  int v = (gid < n) ? cnt[gid] : 0;
  sh[threadIdx.x] = v;
  __syncthreads();
  for (int o = 1; o < 256; o <<= 1) {
    int t = (threadIdx.x >= o) ? sh[threadIdx.x - o] : 0;
    __syncthreads();
    sh[threadIdx.x] += t;
    __syncthreads();
  }
  if (gid < n) rp[gid] = sh[threadIdx.x] - v;  // exclusive within block
  if (threadIdx.x == 255) part[blockIdx.x] = sh[255];
}

__global__ void scan2_kernel(int* part, int B) {
  __shared__ int sh[1024];
  int t = threadIdx.x;
  int v = (t < B) ? part[t] : 0;
  sh[t] = v;
  __syncthreads();
  for (int o = 1; o < 1024; o <<= 1) {
    int u = (t >= o) ? sh[t - o] : 0;
    __syncthreads();
    sh[t] += u;
    __syncthreads();
  }
  if (t < B) part[t] = sh[t] - v;  // exclusive block offsets
}

__global__ void scan3_kernel(int* __restrict__ rp, int* __restrict__ cur,
                             const int* __restrict__ part, int n, int E) {
  int gid = blockIdx.x * 256 + threadIdx.x;
  if (gid < n) {
    int v = rp[gid] + part[blockIdx.x];
    rp[gid] = v;
    cur[gid] = v;
  }
  if (gid == 0) rp[n] = E;
}

__global__ void scatter_kernel(const int* __restrict__ row, const int* __restrict__ col,
                               const float* __restrict__ w, const float* __restrict__ dis,
                               int* __restrict__ cursor, Edge* __restrict__ eg, int E) {
  int e = blockIdx.x * blockDim.x + threadIdx.x;
  if (e < E) {
    int r = row[e], c = col[e];
    int pos = atomicAdd(&cursor[r], 1);
    Edge ed;
    ed.c = c;
    ed.w = dis[r] * w[e] * dis[c];
    eg[pos] = ed;
  }
}

// ---- error init + sigma numerator + mask count (fused, grid-stride) --------
__global__ void __launch_bounds__(256) init_error_kernel(
    float4* __restrict__ x4, const float4* __restrict__ ysoft4,
    const int* __restrict__ ytrue, const void* maskp,
    const int* __restrict__ flag, float* __restrict__ sig,
    int* __restrict__ numel, int n) {
  const int esz = flag[0];
  const int total = n * 10;  // quads
  float asum = 0.f;
  int cnt = 0;
  for (int q = blockIdx.x * blockDim.x + threadIdx.x; q < total;
       q += gridDim.x * blockDim.x) {
    int i = q / 10;
    int c4 = q - i * 10;
    float4 e = make_float4(0.f, 0.f, 0.f, 0.f);
    if (load_mask(maskp, esz, i)) {
      float4 p = ysoft4[q];
      int t = ytrue[i];
      int cb = c4 * 4;
      e.x = ((t == cb) ? 1.f : 0.f) - p.x;
      e.y = ((t == cb + 1) ? 1.f : 0.f) - p.y;
      e.z = ((t == cb + 2) ? 1.f : 0.f) - p.z;
      e.w = ((t == cb + 3) ? 1.f : 0.f) - p.w;
      if (c4 == 0) cnt++;
    }
    x4[q] = e;
    asum += fabsf(e.x) + fabsf(e.y) + fabsf(e.z) + fabsf(e.w);
  }
  // block reduce -> one atomic per block
  for (int o = 32; o > 0; o >>= 1) {
    asum += __shfl_down(asum, o);
    cnt += __shfl_down(cnt, o);
  }
  __shared__ float swf[4];
  __shared__ int swi[4];
  int lane = threadIdx.x & 63, wv = threadIdx.x >> 6;
  if (lane == 0) { swf[wv] = asum; swi[wv] = cnt; }
  __syncthreads();
  if (threadIdx.x == 0) {
    atomicAdd(sig, swf[0] + swf[1] + swf[2] + swf[3]);
    atomicAdd(numel, swi[0] + swi[1] + swi[2] + swi[3]);
  }
}

// ---- propagation step: POST 0 = clip[-1,1], 1 = row softmax ----------------
// 10 lanes per row, float4 per lane; block = 320 threads = 32 rows exactly.
template <int POST>
__global__ void __launch_bounds__(320) prop_step(const float* __restrict__ xin,
                                                 float* __restrict__ xout,
                                                 const int* __restrict__ rp,
                                                 const Edge* __restrict__ eg,
                                                 float alpha, int n) {
  const int t = threadIdx.x;
  const int lr = t / 10;       // 0..31
  const int c4 = t - lr * 10;  // 0..9
  const int i = blockIdx.x * 32 + lr;
  const bool active = (i < n);
  const float4* __restrict__ X4 = (const float4*)xin;
  float4 v = make_float4(0.f, 0.f, 0.f, 0.f);
  if (active) {
    int e0 = rp[i], e1 = rp[i + 1];
    float4 self = X4[i * 10 + c4];
    float4 acc = make_float4(0.f, 0.f, 0.f, 0.f);
    int e = e0;
    for (; e + 3 < e1; e += 4) {  // 4 outstanding gathers
      Edge d0 = eg[e], d1 = eg[e + 1], d2 = eg[e + 2], d3 = eg[e + 3];
      float4 x0 = X4[d0.c * 10 + c4];
      float4 x1 = X4[d1.c * 10 + c4];
      float4 x2 = X4[d2.c * 10 + c4];
      float4 x3 = X4[d3.c * 10 + c4];
      acc.x = fmaf(d0.w, x0.x, acc.x); acc.y = fmaf(d0.w, x0.y, acc.y);
      acc.z = fmaf(d0.w, x0.z, acc.z); acc.w = fmaf(d0.w, x0.w, acc.w);
      acc.x = fmaf(d1.w, x1.x, acc.x); acc.y = fmaf(d1.w, x1.y, acc.y);
      acc.z = fmaf(d1.w, x1.z, acc.z); acc.w = fmaf(d1.w, x1.w, acc.w);
      acc.x = fmaf(d2.w, x2.x, acc.x); acc.y = fmaf(d2.w, x2.y, acc.y);
      acc.z = fmaf(d2.w, x2.z, acc.z); acc.w = fmaf(d2.w, x2.w, acc.w);
      acc.x = fmaf(d3.w, x3.x, acc.x); acc.y = fmaf(d3.w, x3.y, acc.y);
      acc.z = fmaf(d3.w, x3.z, acc.z); acc.w = fmaf(d3.w, x3.w, acc.w);
    }
    for (; e < e1; ++e) {
      Edge d = eg[e];
      float4 xv = X4[d.c * 10 + c4];
      acc.x = fmaf(d.w, xv.x, acc.x); acc.y = fmaf(d.w, xv.y, acc.y);
      acc.z = fmaf(d.w, xv.z, acc.z); acc.w = fmaf(d.w, xv.w, acc.w);
    }
    float beta = 1.f - alpha;
    v.x = alpha * acc.x + beta * self.x;
    v.y = alpha * acc.y + beta * self.y;
    v.z = alpha * acc.z + beta * self.z;
    v.w = alpha * acc.w + beta * self.w;
  }
  if (POST == 0) {
    if (active) {
      float4 o;
      o.x = fminf(1.f, fmaxf(-1.f, v.x));
      o.y = fminf(1.f, fmaxf(-1.f, v.y));
      o.z = fminf(1.f, fmaxf(-1.f, v.z));
      o.w = fminf(1.f, fmaxf(-1.f, v.w));
      ((float4*)xout)[i * 10 + c4] = o;
    }
  } else {
    __shared__ float sh[32][10];
    __shared__ float shr[32];
    float lmax = fmaxf(fmaxf(v.x, v.y), fmaxf(v.z, v.w));
    if (active) sh[lr][c4] = lmax;
    __syncthreads();
    if (active && c4 == 0) {
      float m = sh[lr][0];
#pragma unroll
      for (int k = 1; k < 10; ++k) m = fmaxf(m, sh[lr][k]);
      shr[lr] = m;
    }
    __syncthreads();
    float m = active ? shr[lr] : 0.f;
    float ex = __expf(v.x - m), ey = __expf(v.y - m),
          ez = __expf(v.z - m), ew = __expf(v.w - m);
    if (active) sh[lr][c4] = ex + ey + ez + ew;
    __syncthreads();
    if (active && c4 == 0) {
      float s = sh[lr][0];
#pragma unroll
      for (int k = 1; k < 10; ++k) s += sh[lr][k];
      shr[lr] = s;
    }
    __syncthreads();
    if (active) {
      float inv = 1.f / shr[lr];
      float4 o = make_float4(ex * inv, ey * inv, ez * inv, ew * inv);
      ((float4*)xout)[i * 10 + c4] = o;
    }
  }
}

// ---- scale + y_s -----------------------------------------------------------
__global__ void __launch_bounds__(256) scale_kernel(const float* __restrict__ sm,
                                                    float* __restrict__ out,
                                                    const float* __restrict__ ysoft,
                                                    const int* __restrict__ ytrue,
                                                    const void* maskp,
                                                    const int* __restrict__ flag,
                                                    const float* __restrict__ sig,
                                                    const int* __restrict__ numel, int n) {
  int t = threadIdx.x;
  int lr = t / C_CLS, c = t - lr * C_CLS;
  int i = blockIdx.x * RPB + lr;
  bool active = (lr < RPB) && (i < n);
  __shared__ float sh[RPB][C_CLS];
  __shared__ float shd[RPB];
  float v = 0.f;
  if (active) {
    v = sm[i * C_CLS + c];
    sh[lr][c] = fabsf(v);
  }
  __syncthreads();
  if (active && c == 0) {
    float d = 0.f;
#pragma unroll
    for (int k = 0; k < C_CLS; ++k) d += sh[lr][k];
    shd[lr] = d;
  }
  __syncthreads();
  if (active) {
    float denom = shd[lr];
    float sigma = sig[0] / (float)numel[0];
    float raw = sigma / ((denom > 0.f) ? denom : 1.f);
    float scale = (denom <= 0.f || raw > 1000.f) ? 1.f : raw;
    float yc = ysoft[i * C_CLS + c] + scale * v;
    float oh = (ytrue[i] == c) ? 1.f : 0.f;
    out[i * C_CLS + c] = load_mask(maskp, flag[0], i) ? oh : yc;
  }
}

// ---- launch ---------------------------------------------------------------
extern "C" void kernel_launch(void* const* d_in, const int* in_sizes, int n_in,
                              void* d_out, int out_size, void* d_ws, size_t ws_size,
                              hipStream_t stream) {
  const int* y_true = (const int*)d_in[0];
  const float* y_soft = (const float*)d_in[1];
  const void* maskp = d_in[2];
  const int* ei = (const int*)d_in[3];
  const float* ew = (const float*)d_in[4];
  const int n = in_sizes[0];
  const int E = in_sizes[4];
  const int* row = ei;
  const int* col = ei + E;

  char* ws = (char*)d_ws;
  size_t o = 0;
  auto alloc = [&](size_t bytes) -> void* {
    void* p = ws + o;
    o += (bytes + 255) & ~(size_t)255;
    return p;
  };
  float* xA = (float*)alloc((size_t)n * C_CLS * 4);
  Edge* eg = (Edge*)alloc((size_t)E * 8);
  float* deg = (float*)alloc((size_t)n * 4);   // becomes dis after rsqrt_kernel
  int* cnt = (int*)alloc((size_t)n * 4);
  float* sig = (float*)alloc(4);
  int* numel = (int*)alloc(4);
  int* flag = (int*)alloc(4);
  int* rp = (int*)alloc((size_t)(n + 1) * 4);
  int* cur = (int*)alloc((size_t)n * 4);
  int* part = (int*)alloc(4096);
  float* xB = (float*)d_out;  // d_out doubles as ping-pong buffer

  hipMemsetAsync(deg, 0, (size_t)n * 4, stream);
  hipMemsetAsync(cnt, 0, (size_t)n * 4, stream);
  hipMemsetAsync(sig, 0, 4, stream);
  hipMemsetAsync(numel, 0, 4, stream);

  const int be = (E + 255) / 256;
  const int bn = (n + 255) / 256;
  const int bp32 = (n + 31) / 32;          // prop_step blocks (320 thr, 32 rows)
  const int bsc = (n + RPB - 1) / RPB;     // scale_kernel blocks

  detect_kernel<<<1, 256, 0, stream>>>((const unsigned int*)maskp, flag);
  hist_kernel<<<be, 256, 0, stream>>>(row, ew, deg, cnt, E);
  rsqrt_kernel<<<bn, 256, 0, stream>>>(deg, n);
  scan1_kernel<<<bn, 256, 0, stream>>>(cnt, rp, part, n);
  scan2_kernel<<<1, 1024, 0, stream>>>(part, bn);
  scan3_kernel<<<bn, 256, 0, stream>>>(rp, cur, part, n, E);
  scatter_kernel<<<be, 256, 0, stream>>>(row, col, ew, deg, cur, eg, E);
  init_error_kernel<<<512, 256, 0, stream>>>((float4*)xA, (const float4*)y_soft,
                                             y_true, maskp, flag, sig, numel, n);

  // Phase 1: correct (alpha=0.9, clip). Start a=xA -> after 10 steps result in xA.
  float* a = xA;
  float* b = xB;
  for (int k = 0; k < 10; ++k) {
    prop_step<0><<<bp32, 320, 0, stream>>>(a, b, rp, eg, 0.9f, n);
    float* t = a; a = b; b = t;
  }
  // a == xA (smoothed error). Scale + y_s written into d_out.
  scale_kernel<<<bsc, 256, 0, stream>>>(a, b, y_soft, y_true, maskp, flag, sig, numel, n);
  { float* t = a; a = b; b = t; }  // a = d_out (y_s), b = xA

  // Phase 2: smooth (alpha=0.8, softmax). 10 steps starting at d_out -> ends in d_out.
  for (int k = 0; k < 10; ++k) {
    prop_step<1><<<bp32, 320, 0, stream>>>(a, b, rp, eg, 0.8f, n);
    float* t = a; a = b; b = t;
  }
}